// Round 20
// baseline (195.610 us; speedup 1.0000x reference)
//
#include <hip/hip_runtime.h>
#include <hip/hip_bf16.h>
#include <math.h>

// GAT forward. N=4096, Fin=512, H=8, D=64, C=64.
// Round 20 = round 19 with the attention pipeline SKEWED one tile:
// per iteration: mm8(tile it-1) [MFMA, reads sealed pS[buf^1]] THEN
// pph(tile it) [VALU, writes pS[buf]] THEN one barrier. MFMA and the
// p-phase VALU now co-issue (independent pipes); register liveness is
// unchanged vs r19 (still {cur,next}x{B,uv,m}) so VGPR/occupancy hold.

#define N_NODES 4096
#define FIN 512
#define NHEAD 8
#define DHEAD 64
#define NCLS 64
#define NW 64

typedef unsigned short u16;
typedef unsigned long long u64;
typedef __attribute__((ext_vector_type(8))) short bf16x8;
typedef __attribute__((ext_vector_type(4))) float f32x4;

__device__ __forceinline__ float lrelu02(float x) { return x > 0.f ? x : 0.2f * x; }
__device__ __forceinline__ u16 bf16u(float x) {
    __hip_bfloat16 h = __float2bfloat16(x);
    return __builtin_bit_cast(unsigned short, h);
}
__device__ __forceinline__ float b2f(u16 v) {
    unsigned u = (unsigned)v << 16;
    return __builtin_bit_cast(float, u);
}
__device__ __forceinline__ f32x4 mfma16(bf16x8 a, bf16x8 b, f32x4 c) {
    return __builtin_amdgcn_mfma_f32_16x16x32_bf16(a, b, c, 0, 0, 0);
}
__device__ __forceinline__ unsigned fkey(float f) {
    unsigned u = __builtin_bit_cast(unsigned, f);
    return (u & 0x80000000u) ? ~u : (u | 0x80000000u);
}
__device__ __forceinline__ float funkey(unsigned k) {
    unsigned u = (k & 0x80000000u) ? (k ^ 0x80000000u) : ~k;
    return __builtin_bit_cast(float, u);
}

// ---------------- prep: pack adj -> mb[row][jword], bf16 cvts, weight T ------
__global__ __launch_bounds__(256) void prep(
    const int* __restrict__ adj, u64* __restrict__ mb, unsigned* __restrict__ gmk,
    const float* __restrict__ x, u16* __restrict__ xB,
    const float* __restrict__ W1, u16* __restrict__ W1B,
    const float* __restrict__ W, const float* __restrict__ Wo,
    u16* __restrict__ WBt, u16* __restrict__ WoBt) {
    __shared__ alignas(16) u16 T[64][72];
    const int bid = blockIdx.x, t = threadIdx.x;
    if (bid < 1024) {
        if (bid == 0 && t < 16) gmk[t] = 0u;
        int nwaves = (1024 * 256) >> 6;
        int wid = (bid * 256 + t) >> 6;
        int lane = t & 63;
        for (int w = wid; w < N_NODES * NW; w += nwaves) {
            int i = w >> 6, wc = w & 63;
            int j = (wc << 6) | lane;
            u64 m = __ballot(adj[(size_t)i * N_NODES + j] > 0);
            if (lane == 0) mb[w] = m;
        }
    } else if (bid < 5120) {
        int i = (bid - 1024) * 256 + t;
        const float* s;
        u16* d;
        if (i < N_NODES * FIN / 4) { s = x; d = xB; }
        else { i -= N_NODES * FIN / 4; s = W1; d = W1B; }
        float4 v = ((const float4*)s)[i];
        ushort4 o = {bf16u(v.x), bf16u(v.y), bf16u(v.z), bf16u(v.w)};
        ((ushort4*)d)[i] = o;
    } else {
        int idx = bid - 5120;
        int y = idx >> 3, xb = idx & 7;
        const float* src = (y < 8) ? W + (size_t)y * FIN * DHEAD : Wo;
        u16* d = (y < 8) ? WBt + (size_t)y * DHEAD * FIN : WoBt;
        const int j0 = xb * 64;
        const int row = t & 63, g = t >> 6;
        #pragma unroll
        for (int k = 0; k < 16; k += 4) {
            float4 v = *(const float4*)(src + (size_t)(j0 + row) * 64 + g * 16 + k);
            T[g * 16 + k + 0][row] = bf16u(v.x);
            T[g * 16 + k + 1][row] = bf16u(v.y);
            T[g * 16 + k + 2][row] = bf16u(v.z);
            T[g * 16 + k + 3][row] = bf16u(v.w);
        }
        __syncthreads();
        const int dd = t >> 2, jc = (t & 3) * 16;
        *(uint4*)(d + (size_t)dd * FIN + j0 + jc) = *(const uint4*)&T[dd][jc];
        *(uint4*)(d + (size_t)dd * FIN + j0 + jc + 8) = *(const uint4*)&T[dd][jc + 8];
    }
}

// ---------------- fused MFMA GEMM ----------------
// AMODE 0: A = plain bf16 row-major [M][lda].
// AMODE 1: A = elu((part0+part1)*inv_den) inline from bf16 partials (K=512).
template <int AMODE>
__global__ __launch_bounds__(256) void gemm_fused(
    const u16* __restrict__ A, int lda, const u16* __restrict__ Bt, int ldb,
    const float* __restrict__ a1a, const float* __restrict__ a2a,
    u16* __restrict__ WhBT, float* __restrict__ f1o, float* __restrict__ f2o,
    unsigned* __restrict__ gmk, int K, const float* __restrict__ denp) {
    __shared__ alignas(16) u16 T[64][72];
    const int t = threadIdx.x, lane = t & 63, wv = t >> 6;
    const int c16 = lane & 15, kg = lane >> 4;
    const int h = blockIdx.x;
    const int bm = blockIdx.y * 64;
    const int arow = bm + wv * 16 + c16;
    const u16* Bp = Bt + (size_t)(h * 64 + c16) * ldb + kg * 8;
    f32x4 acc[4] = {};
    if constexpr (AMODE == 0) {
        const u16* Ap = A + (size_t)arow * lda + kg * 8;
        #pragma unroll 4
        for (int k0 = 0; k0 < K; k0 += 32) {
            bf16x8 a = *(const bf16x8*)(Ap + k0);
            #pragma unroll
            for (int ct = 0; ct < 4; ++ct) {
                bf16x8 b = *(const bf16x8*)(Bp + (size_t)ct * 16 * ldb + k0);
                acc[ct] = mfma16(a, b, acc[ct]);
            }
        }
    } else {
        const u16* P0 = A + (size_t)arow * 512 + kg * 8;
        const u16* P1 = P0 + (size_t)N_NODES * 512;
        float inv[8];
        #pragma unroll
        for (int hh = 0; hh < 8; ++hh) {
            float d = denp[(size_t)hh * N_NODES + arow] +
                      denp[(size_t)(8 + hh) * N_NODES + arow];
            inv[hh] = d > 0.f ? 1.f / d : 0.f;
        }
        #pragma unroll
        for (int k0 = 0; k0 < 512; k0 += 32) {
            const int hh = k0 >> 6;
            bf16x8 q0 = *(const bf16x8*)(P0 + k0);
            bf16x8 q1 = *(const bf16x8*)(P1 + k0);
            bf16x8 a;
            #pragma unroll
            for (int e = 0; e < 8; ++e) {
                float v = (b2f((u16)q0[e]) + b2f((u16)q1[e])) * inv[hh];
                float el = fmaxf(v, 0.f) + __expf(fminf(v, 0.f)) - 1.f;
                a[e] = (short)bf16u(el);
            }
            #pragma unroll
            for (int ct = 0; ct < 4; ++ct) {
                bf16x8 b = *(const bf16x8*)(Bp + (size_t)ct * 16 * ldb + k0);
                acc[ct] = mfma16(a, b, acc[ct]);
            }
        }
    }
    float a1v[4], a2v[4];
    #pragma unroll
    for (int ct = 0; ct < 4; ++ct) {
        a1v[ct] = a1a[h * 64 + ct * 16 + c16];
        a2v[ct] = a2a[h * 64 + ct * 16 + c16];
    }
    float mx = -1e30f;
    #pragma unroll
    for (int r = 0; r < 4; ++r) {
        float s1 = 0.f, s2 = 0.f;
        int rl = wv * 16 + kg * 4 + r;
        #pragma unroll
        for (int ct = 0; ct < 4; ++ct) {
            float v = acc[ct][r];
            s1 = fmaf(v, a1v[ct], s1);
            s2 = fmaf(v, a2v[ct], s2);
            T[ct * 16 + c16][rl] = bf16u(v);
        }
        #pragma unroll
        for (int off = 1; off < 16; off <<= 1) {
            s1 += __shfl_xor(s1, off, 64);
            s2 += __shfl_xor(s2, off, 64);
        }
        if (c16 == 0) {
            f1o[(size_t)h * N_NODES + bm + rl] = s1;
            f2o[(size_t)h * N_NODES + bm + rl] = s2;
        }
        mx = fmaxf(mx, s2);
    }
    mx = fmaxf(mx, __shfl_xor(mx, 16, 64));
    mx = fmaxf(mx, __shfl_xor(mx, 32, 64));
    if (lane == 0) atomicMax(&gmk[h], fkey(mx));
    __syncthreads();
    const int dd = t >> 2, jc = (t & 3) * 16;
    u16* dst = WhBT + (size_t)(h * 64 + dd) * N_NODES + bm;
    *(uint4*)(dst + jc) = *(const uint4*)&T[dd][jc];
    *(uint4*)(dst + jc + 8) = *(const uint4*)&T[dd][jc + 8];
}

// ---------------- per-row / per-col softmax coefficients ----------------
__global__ void coefk(const float* __restrict__ f1, const float* __restrict__ f2,
                      const unsigned* __restrict__ gmk, float2* __restrict__ rowc,
                      float2* __restrict__ uv) {
    int h = blockIdx.y;
    int i = blockIdx.x * 256 + threadIdx.x;
    float g = funkey(gmk[h]);
    float a = f1[(size_t)h * N_NODES + i];
    float s = a + g;
    float M = lrelu02(s);
    rowc[(size_t)h * N_NODES + i] = make_float2(__expf(s - M), __expf(0.2f * s - M));
    float b = f2[(size_t)h * N_NODES + i] - g;
    uv[(size_t)h * N_NODES + i] = make_float2(__expf(b), __expf(0.2f * b));
}

// ---------------- attention v3s: skewed pipeline (mm8 of prev tile first) ----
// OUTF 1: bf16 row-major partial [js][4096][512] (NH=8)
// OUTF 3: fp32 transposed partial [js][64][4096]  (NH=1)
template <int NH, int ROWS, int JSPLIT, int OUTF>
__global__ __launch_bounds__(256) void attn_v3(
    const u16* __restrict__ WhB, const float2* __restrict__ uv,
    const float2* __restrict__ rowc, const u64* __restrict__ mb,
    void* __restrict__ outp, float* __restrict__ denP) {
    constexpr int NQ = ROWS / 4;
    constexpr int NMT = ROWS / 16;
    constexpr int NJT = (N_NODES / 64) / JSPLIT;
    __shared__ alignas(16) u16 pS[2][ROWS][64];
    __shared__ float Tof[(OUTF == 3) ? 64 * (ROWS + 1) : 1];
    const int b = blockIdx.x;
    int h, ib, js;
    if (NH == 8) { h = b & 7; int r = b >> 3; js = r % JSPLIT; ib = r / JSPLIT; }
    else { h = 0; js = b % JSPLIT; ib = b / JSPLIT; }
    const int i0 = ib * ROWS;
    const int jt0 = js * NJT;
    const int t = threadIdx.x, lane = t & 63, wv = t >> 6;
    const int wv_u = __builtin_amdgcn_readfirstlane(wv);

    const float2* __restrict__ uvp = uv + (size_t)h * N_NODES;
    const float2* __restrict__ rcp = rowc + (size_t)h * N_NODES;
    const u64* __restrict__ mbp = mb + (size_t)(i0 + wv_u) * NW + jt0;

    float Aq[NQ], Bq[NQ], den[NQ];
    #pragma unroll
    for (int q = 0; q < NQ; ++q) {
        float2 rc = rcp[i0 + q * 4 + wv];
        Aq[q] = rc.x; Bq[q] = rc.y; den[q] = 0.f;
    }
    const int wcE = lane ^ (wv << 3);
    const int wcO = lane ^ ((wv + 4) << 3);
    const int kg = lane >> 4, c16 = lane & 15;
    const int ocol = wv * 16 + c16;
    const u16* bptr = WhB + ((size_t)h * 64 + ocol) * N_NODES + jt0 * 64 + kg * 8;
    const int sw8 = (c16 & 7) << 3;
    f32x4 acc[NMT] = {};

    // p-phase helper (writes pS[bufI] for the tile whose uv/m are passed)
    auto pph = [&](int bufI, float2 u, const u64* mm) {
        #pragma unroll
        for (int q = 0; q < NQ; ++q) {
            float tv = fmaxf(Aq[q] * u.x, Bq[q] * u.y);
            float p;
            asm("v_cndmask_b32 %0, 0, %1, %2" : "=v"(p) : "v"(tv), "s"(mm[q]));
            den[q] += p;
            pS[bufI][q * 4 + wv][(q & 1) ? wcO : wcE] = bf16u(p);
        }
    };
    auto mm8 = [&](int bufI, bf16x8 v0, bf16x8 v1) {
        __builtin_amdgcn_s_setprio(1);
        #pragma unroll
        for (int mt = 0; mt < NMT; ++mt) {
            const u16* ap = &pS[bufI][mt * 16 + c16][0];
            bf16x8 a0 = *(const bf16x8*)&ap[(kg * 8) ^ sw8];
            bf16x8 a1 = *(const bf16x8*)&ap[(32 + kg * 8) ^ sw8];
            acc[mt] = mfma16(a0, v0, acc[mt]);
            acc[mt] = mfma16(a1, v1, acc[mt]);
        }
        __builtin_amdgcn_s_setprio(0);
    };

    // prologue: pph(tile 0), then prefetch B(0) [for mm8 at it=1] and uv/m(1)
    {
        float2 u0 = uvp[jt0 * 64 + lane];
        u64 m0[NQ];
        #pragma unroll
        for (int q = 0; q < NQ; ++q) m0[q] = mbp[q * 4 * NW];
        pph(0, u0, m0);
    }
    bf16x8 b0 = *(const bf16x8*)(bptr);          // B(0)
    bf16x8 b1 = *(const bf16x8*)(bptr + 32);
    float2 uvv = uvp[(jt0 + (NJT > 1 ? 1 : 0)) * 64 + lane];  // uv(1)
    u64 m[NQ];
    #pragma unroll
    for (int q = 0; q < NQ; ++q) m[q] = mbp[q * 4 * NW + (NJT > 1 ? 1 : 0)];
    __syncthreads();  // seal pS[0]

    for (int it = 1; it < NJT; ++it) {
        const int buf = it & 1;
        const int nit = (it + 1 < NJT) ? it + 1 : it;
        // prefetch: B(it) for mm8 at it+1; uv/m(it+1) for pph at it+1
        bf16x8 nb0 = *(const bf16x8*)(bptr + (size_t)it * 64);
        bf16x8 nb1 = *(const bf16x8*)(bptr + (size_t)it * 64 + 32);
        float2 nuv = uvp[(jt0 + nit) * 64 + lane];
        u64 nm[NQ];
        #pragma unroll
        for (int q = 0; q < NQ; ++q) nm[q] = mbp[q * 4 * NW + nit];
        // MFMA for tile it-1 (pS[buf^1] sealed) co-issues with p-phase VALU
        mm8(buf ^ 1, b0, b1);
        // p-phase for tile it
        pph(buf, uvv, m);
        __syncthreads();
        b0 = nb0; b1 = nb1; uvv = nuv;
        #pragma unroll
        for (int q = 0; q < NQ; ++q) m[q] = nm[q];
    }
    // epilogue: MFMA for last tile (b0/b1 hold B(NJT-1) after final shift)
    mm8((NJT - 1) & 1, b0, b1);

    #pragma unroll
    for (int q = 0; q < NQ; ++q) {
        float s = den[q];
        #pragma unroll
        for (int off = 32; off; off >>= 1) s += __shfl_xor(s, off, 64);
        den[q] = s;
    }

    if constexpr (OUTF == 1) {
        if (lane == 0) {
            #pragma unroll
            for (int q = 0; q < NQ; ++q)
                denP[(size_t)js * (8 * N_NODES) + (size_t)h * N_NODES + i0 + q * 4 + wv] = den[q];
        }
        u16* dst = (u16*)outp + (size_t)js * N_NODES * 512;
        #pragma unroll
        for (int mt = 0; mt < NMT; ++mt)
            #pragma unroll
            for (int r = 0; r < 4; ++r)
                dst[(size_t)(i0 + mt * 16 + kg * 4 + r) * 512 + h * 64 + ocol] =
                    bf16u(acc[mt][r]);
    } else {
        if (lane == 0) {
            #pragma unroll
            for (int q = 0; q < NQ; ++q)
                denP[(size_t)js * N_NODES + i0 + q * 4 + wv] = den[q];
        }
        #pragma unroll
        for (int mt = 0; mt < NMT; ++mt)
            #pragma unroll
            for (int r = 0; r < 4; ++r)
                Tof[ocol * (ROWS + 1) + mt * 16 + kg * 4 + r] = acc[mt][r];
        __syncthreads();
        const int c = t >> 2, r0 = (t & 3) * 8;
        float* dst = (float*)outp + (size_t)js * 64 * N_NODES + (size_t)c * N_NODES + i0 + r0;
        float4 v0 = {Tof[c * (ROWS + 1) + r0 + 0], Tof[c * (ROWS + 1) + r0 + 1],
                     Tof[c * (ROWS + 1) + r0 + 2], Tof[c * (ROWS + 1) + r0 + 3]};
        float4 v1 = {Tof[c * (ROWS + 1) + r0 + 4], Tof[c * (ROWS + 1) + r0 + 5],
                     Tof[c * (ROWS + 1) + r0 + 6], Tof[c * (ROWS + 1) + r0 + 7]};
        *(float4*)(dst) = v0;
        *(float4*)(dst + 4) = v1;
    }
}

// ---------------- combine attn1 partials (8-way) + ELU + log_softmax ---------
__global__ __launch_bounds__(256) void combine1_lsm(
    const float* __restrict__ partT, const float* __restrict__ denp,
    u16* __restrict__ lsT) {
    __shared__ float vb[N_NODES];
    __shared__ float r[256];
    const int c = blockIdx.x, t = threadIdx.x;
    float m = -1e30f;
    for (int i = t * 4; i < N_NODES; i += 1024) {
        float4 s = {0.f, 0.f, 0.f, 0.f}, d = {0.f, 0.f, 0.f, 0.f};
        #pragma unroll
        for (int js = 0; js < 8; ++js) {
            float4 pv = *(const float4*)(partT + (size_t)js * 64 * N_NODES +
                                         (size_t)c * N_NODES + i);
            float4 dv = *(const float4*)(denp + (size_t)js * N_NODES + i);
            s.x += pv.x; s.y += pv.y; s.z += pv.z; s.w += pv.w;
            d.x += dv.x; d.y += dv.y; d.z += dv.z; d.w += dv.w;
        }
        float vv[4] = {d.x > 0.f ? s.x / d.x : 0.f, d.y > 0.f ? s.y / d.y : 0.f,
                       d.z > 0.f ? s.z / d.z : 0.f, d.w > 0.f ? s.w / d.w : 0.f};
        #pragma unroll
        for (int k = 0; k < 4; ++k) {
            float e = vv[k] > 0.f ? vv[k] : expm1f(vv[k]);
            vb[i + k] = e;
            m = fmaxf(m, e);
        }
    }
    r[t] = m;
    __syncthreads();
    for (int s = 128; s; s >>= 1) {
        if (t < s) r[t] = fmaxf(r[t], r[t + s]);
        __syncthreads();
    }
    m = r[0];
    __syncthreads();
    float sum = 0.f;
    for (int i = t; i < N_NODES; i += 256) sum += __expf(vb[i] - m);
    r[t] = sum;
    __syncthreads();
    for (int s = 128; s; s >>= 1) {
        if (t < s) r[t] += r[t + s];
        __syncthreads();
    }
    float lse = m + __logf(r[0]);
    for (int i = t * 4; i < N_NODES; i += 1024) {
        ushort4 o = {bf16u(vb[i] - lse), bf16u(vb[i + 1] - lse),
                     bf16u(vb[i + 2] - lse), bf16u(vb[i + 3] - lse)};
        *(ushort4*)(lsT + (size_t)c * N_NODES + i) = o;
    }
}

// ---------------- mlp1: split-K MFMA  part[ks][64 c][512 o] ----------------
__global__ __launch_bounds__(256) void mlp1_mfma(
    const u16* __restrict__ lsT, const u16* __restrict__ W1B,
    float* __restrict__ part) {
    const int t = threadIdx.x, lane = t & 63, wv = t >> 6;
    const int c16 = lane & 15, kg = lane >> 4;
    const int ks = blockIdx.x & 15;
    const int bn = (blockIdx.x >> 4) * 64;
    const int kb = ks * 256;
    const u16* Ap = lsT + (size_t)(wv * 16 + c16) * N_NODES + kb + kg * 8;
    const u16* Bp = W1B + (size_t)(bn + c16) * N_NODES + kb + kg * 8;
    f32x4 acc[4] = {};
    #pragma unroll
    for (int k0 = 0; k0 < 256; k0 += 32) {
        bf16x8 a = *(const bf16x8*)(Ap + k0);
        #pragma unroll
        for (int ct = 0; ct < 4; ++ct) {
            bf16x8 b = *(const bf16x8*)(Bp + (size_t)ct * 16 * N_NODES + k0);
            acc[ct] = mfma16(a, b, acc[ct]);
        }
    }
    float* dst = part + (size_t)ks * 64 * 512;
    #pragma unroll
    for (int ct = 0; ct < 4; ++ct)
        #pragma unroll
        for (int r = 0; r < 4; ++r)
            dst[(size_t)(wv * 16 + kg * 4 + r) * 512 + bn + ct * 16 + c16] = acc[ct][r];
}

// ---------------- fused: reduce split-K + bias + leaky, then y @ W2^T --------
__global__ __launch_bounds__(256) void mlp2f(
    const float* __restrict__ part, const float* __restrict__ b1,
    const float* __restrict__ W2, const float* __restrict__ b2,
    float* __restrict__ out) {
    __shared__ alignas(16) float row[512];
    const int c = blockIdx.x, t = threadIdx.x;
    #pragma unroll
    for (int half = 0; half < 2; ++half) {
        int o = t + half * 256;
        float s = 0.f;
        #pragma unroll
        for (int ks = 0; ks < 16; ++ks)
            s += part[(size_t)ks * 32768 + (size_t)c * 512 + o];
        s += b1[o];
        row[o] = s > 0.f ? s : 0.1f * s;
    }
    __syncthreads();
    float acc = 0.f;
    #pragma unroll 4
    for (int o = 0; o < 512; o += 4) {
        float4 w4 = *(const float4*)(W2 + (size_t)t * 512 + o);
        float4 r4 = *(const float4*)(&row[o]);
        acc += w4.x * r4.x + w4.y * r4.y + w4.z * r4.z + w4.w * r4.w;
    }
    out[(size_t)c * 256 + t] = acc + b2[t];
}

extern "C" void kernel_launch(void* const* d_in, const int* in_sizes, int n_in,
                              void* d_out, int out_size, void* d_ws, size_t ws_size,
                              hipStream_t stream) {
    const float* x   = (const float*)d_in[0];
    const int*   adj = (const int*)d_in[1];
    const float* W   = (const float*)d_in[2];
    const float* a1  = (const float*)d_in[3];
    const float* a2  = (const float*)d_in[4];
    const float* Wo  = (const float*)d_in[5];
    const float* ao1 = (const float*)d_in[6];
    const float* ao2 = (const float*)d_in[7];
    const float* W1  = (const float*)d_in[8];
    const float* b1  = (const float*)d_in[9];
    const float* W2  = (const float*)d_in[10];
    const float* b2  = (const float*)d_in[11];
    float* out = (float*)d_out;

    char* ws = (char*)d_ws;
    size_t off = 0;
    auto alloc = [&](size_t bytes) {
        void* p = ws + off;
        off += (bytes + 255) & ~(size_t)255;
        return p;
    };
    u64*     mb     = (u64*)alloc((size_t)N_NODES * NW * 8);
    u16*     xB     = (u16*)alloc((size_t)N_NODES * FIN * 2);
    u16*     WBt    = (u16*)alloc((size_t)NHEAD * DHEAD * FIN * 2);
    u16*     WoBt   = (u16*)alloc((size_t)DHEAD * FIN * 2);
    u16*     W1B    = (u16*)alloc((size_t)512 * N_NODES * 2);
    u16*     WhB    = (u16*)alloc((size_t)NHEAD * DHEAD * N_NODES * 2);
    u16*     WhoB   = (u16*)alloc((size_t)DHEAD * N_NODES * 2);
    u16*     part8  = (u16*)alloc((size_t)2 * N_NODES * 512 * 2);     // 8 MB bf16
    char*    pool   = (char*)alloc((size_t)12 << 20);                 // 12 MB pool
    float*   den8   = (float*)alloc((size_t)2 * 8 * N_NODES * 4);
    float*   f1b    = (float*)alloc((size_t)9 * N_NODES * 4);
    float*   f2b    = (float*)alloc((size_t)9 * N_NODES * 4);
    unsigned* gmk   = (unsigned*)alloc(16 * 4);
    float2*  rowc   = (float2*)alloc((size_t)9 * N_NODES * 8);
    float2*  uvb    = (float2*)alloc((size_t)9 * N_NODES * 8);
    float*   partT1 = (float*)pool;                                    // 8 MB [8][64][4096]
    float*   den1   = (float*)(pool + ((size_t)8 << 20));              // 128 KB
    u16*     lsT    = (u16*)(pool + ((size_t)8 << 20) + (256 << 10));  // 512 KB
    float*   part   = (float*)(pool + ((size_t)9 << 20));              // 2 MB
    (void)ws_size; (void)in_sizes; (void)n_in; (void)out_size;

    prep<<<5192, 256, 0, stream>>>(adj, mb, gmk, x, xB, W1, W1B, W, Wo, WBt, WoBt);
    // layer 1
    gemm_fused<0><<<dim3(8, 64), 256, 0, stream>>>(xB, FIN, WBt, FIN, a1, a2,
                                                   WhB, f1b, f2b, gmk, FIN, nullptr);
    coefk<<<dim3(16, 8), 256, 0, stream>>>(f1b, f2b, gmk, rowc, uvb);
    attn_v3<8, 64, 2, 1><<<(N_NODES / 64) * 2 * 8, 256, 0, stream>>>(
        WhB, uvb, rowc, mb, part8, den8);
    // layer 2: gemm consumes the bf16 partials + dens directly (combine fused)
    gemm_fused<1><<<dim3(1, 64), 256, 0, stream>>>(part8, 512, WoBt, FIN, ao1, ao2,
                                                   WhoB, f1b + (size_t)8 * N_NODES,
                                                   f2b + (size_t)8 * N_NODES, gmk + 8,
                                                   FIN, den8);
    coefk<<<dim3(16, 1), 256, 0, stream>>>(f1b + (size_t)8 * N_NODES,
                                           f2b + (size_t)8 * N_NODES, gmk + 8,
                                           rowc + (size_t)8 * N_NODES,
                                           uvb + (size_t)8 * N_NODES);
    attn_v3<1, 32, 8, 3><<<(N_NODES / 32) * 8, 256, 0, stream>>>(
        WhoB, uvb + (size_t)8 * N_NODES, rowc + (size_t)8 * N_NODES, mb, partT1, den1);
    combine1_lsm<<<64, 256, 0, stream>>>(partT1, den1, lsT);
    // MLP head
    mlp1_mfma<<<128, 256, 0, stream>>>(lsT, W1B, part);
    mlp2f<<<64, 256, 0, stream>>>(part, b1, W2, b2, out);
}

// Round 21
// 193.518 us; speedup vs baseline: 1.0108x; 1.0108x over previous
//
#include <hip/hip_runtime.h>
#include <hip/hip_bf16.h>
#include <math.h>

// GAT forward. N=4096, Fin=512, H=8, D=64, C=64.
// Round 21 = exact revert to the round-19 champion (193.6us, best measured).
// r20's pipeline skew was neutral-to-negative (VGPR 60->64, MfmaUtil down):
// cross-wave overlap already covers the p-phase/MFMA co-issue (m114), so the
// explicit skew only added register pressure. Final configuration:
//  - attn_v3 (r7 structure): 64-wide tiles, 1-tile register prefetch,
//    dbuf swizzled pS, 1 barrier/tile, SGPR lane-mask cndmask, setprio(1).
//  - attn8: ROWS=64/JSPLIT=2, bf16 partials; attn1: ROWS=32/JSPLIT=8.
//  - gemm2 fuses partial-combine + den-normalize + ELU into its A-load.
//  - prep mega-kernel (pack+cvt+wT), mlp2f fusion. 10 launches.

#define N_NODES 4096
#define FIN 512
#define NHEAD 8
#define DHEAD 64
#define NCLS 64
#define NW 64

typedef unsigned short u16;
typedef unsigned long long u64;
typedef __attribute__((ext_vector_type(8))) short bf16x8;
typedef __attribute__((ext_vector_type(4))) float f32x4;

__device__ __forceinline__ float lrelu02(float x) { return x > 0.f ? x : 0.2f * x; }
__device__ __forceinline__ u16 bf16u(float x) {
    __hip_bfloat16 h = __float2bfloat16(x);
    return __builtin_bit_cast(unsigned short, h);
}
__device__ __forceinline__ float b2f(u16 v) {
    unsigned u = (unsigned)v << 16;
    return __builtin_bit_cast(float, u);
}
__device__ __forceinline__ f32x4 mfma16(bf16x8 a, bf16x8 b, f32x4 c) {
    return __builtin_amdgcn_mfma_f32_16x16x32_bf16(a, b, c, 0, 0, 0);
}
__device__ __forceinline__ unsigned fkey(float f) {
    unsigned u = __builtin_bit_cast(unsigned, f);
    return (u & 0x80000000u) ? ~u : (u | 0x80000000u);
}
__device__ __forceinline__ float funkey(unsigned k) {
    unsigned u = (k & 0x80000000u) ? (k ^ 0x80000000u) : ~k;
    return __builtin_bit_cast(float, u);
}

// ---------------- prep: pack adj -> mb[row][jword], bf16 cvts, weight T ------
__global__ __launch_bounds__(256) void prep(
    const int* __restrict__ adj, u64* __restrict__ mb, unsigned* __restrict__ gmk,
    const float* __restrict__ x, u16* __restrict__ xB,
    const float* __restrict__ W1, u16* __restrict__ W1B,
    const float* __restrict__ W, const float* __restrict__ Wo,
    u16* __restrict__ WBt, u16* __restrict__ WoBt) {
    __shared__ alignas(16) u16 T[64][72];
    const int bid = blockIdx.x, t = threadIdx.x;
    if (bid < 1024) {
        if (bid == 0 && t < 16) gmk[t] = 0u;
        int nwaves = (1024 * 256) >> 6;
        int wid = (bid * 256 + t) >> 6;
        int lane = t & 63;
        for (int w = wid; w < N_NODES * NW; w += nwaves) {
            int i = w >> 6, wc = w & 63;
            int j = (wc << 6) | lane;
            u64 m = __ballot(adj[(size_t)i * N_NODES + j] > 0);
            if (lane == 0) mb[w] = m;
        }
    } else if (bid < 5120) {
        int i = (bid - 1024) * 256 + t;
        const float* s;
        u16* d;
        if (i < N_NODES * FIN / 4) { s = x; d = xB; }
        else { i -= N_NODES * FIN / 4; s = W1; d = W1B; }
        float4 v = ((const float4*)s)[i];
        ushort4 o = {bf16u(v.x), bf16u(v.y), bf16u(v.z), bf16u(v.w)};
        ((ushort4*)d)[i] = o;
    } else {
        int idx = bid - 5120;
        int y = idx >> 3, xb = idx & 7;
        const float* src = (y < 8) ? W + (size_t)y * FIN * DHEAD : Wo;
        u16* d = (y < 8) ? WBt + (size_t)y * DHEAD * FIN : WoBt;
        const int j0 = xb * 64;
        const int row = t & 63, g = t >> 6;
        #pragma unroll
        for (int k = 0; k < 16; k += 4) {
            float4 v = *(const float4*)(src + (size_t)(j0 + row) * 64 + g * 16 + k);
            T[g * 16 + k + 0][row] = bf16u(v.x);
            T[g * 16 + k + 1][row] = bf16u(v.y);
            T[g * 16 + k + 2][row] = bf16u(v.z);
            T[g * 16 + k + 3][row] = bf16u(v.w);
        }
        __syncthreads();
        const int dd = t >> 2, jc = (t & 3) * 16;
        *(uint4*)(d + (size_t)dd * FIN + j0 + jc) = *(const uint4*)&T[dd][jc];
        *(uint4*)(d + (size_t)dd * FIN + j0 + jc + 8) = *(const uint4*)&T[dd][jc + 8];
    }
}

// ---------------- fused MFMA GEMM ----------------
// AMODE 0: A = plain bf16 row-major [M][lda].
// AMODE 1: A = elu((part0+part1)*inv_den) inline from bf16 partials (K=512).
template <int AMODE>
__global__ __launch_bounds__(256) void gemm_fused(
    const u16* __restrict__ A, int lda, const u16* __restrict__ Bt, int ldb,
    const float* __restrict__ a1a, const float* __restrict__ a2a,
    u16* __restrict__ WhBT, float* __restrict__ f1o, float* __restrict__ f2o,
    unsigned* __restrict__ gmk, int K, const float* __restrict__ denp) {
    __shared__ alignas(16) u16 T[64][72];
    const int t = threadIdx.x, lane = t & 63, wv = t >> 6;
    const int c16 = lane & 15, kg = lane >> 4;
    const int h = blockIdx.x;
    const int bm = blockIdx.y * 64;
    const int arow = bm + wv * 16 + c16;
    const u16* Bp = Bt + (size_t)(h * 64 + c16) * ldb + kg * 8;
    f32x4 acc[4] = {};
    if constexpr (AMODE == 0) {
        const u16* Ap = A + (size_t)arow * lda + kg * 8;
        #pragma unroll 4
        for (int k0 = 0; k0 < K; k0 += 32) {
            bf16x8 a = *(const bf16x8*)(Ap + k0);
            #pragma unroll
            for (int ct = 0; ct < 4; ++ct) {
                bf16x8 b = *(const bf16x8*)(Bp + (size_t)ct * 16 * ldb + k0);
                acc[ct] = mfma16(a, b, acc[ct]);
            }
        }
    } else {
        const u16* P0 = A + (size_t)arow * 512 + kg * 8;
        const u16* P1 = P0 + (size_t)N_NODES * 512;
        float inv[8];
        #pragma unroll
        for (int hh = 0; hh < 8; ++hh) {
            float d = denp[(size_t)hh * N_NODES + arow] +
                      denp[(size_t)(8 + hh) * N_NODES + arow];
            inv[hh] = d > 0.f ? 1.f / d : 0.f;
        }
        #pragma unroll
        for (int k0 = 0; k0 < 512; k0 += 32) {
            const int hh = k0 >> 6;  // 32-wide strip never crosses a 64-col head
            bf16x8 q0 = *(const bf16x8*)(P0 + k0);
            bf16x8 q1 = *(const bf16x8*)(P1 + k0);
            bf16x8 a;
            #pragma unroll
            for (int e = 0; e < 8; ++e) {
                float v = (b2f((u16)q0[e]) + b2f((u16)q1[e])) * inv[hh];
                float el = fmaxf(v, 0.f) + __expf(fminf(v, 0.f)) - 1.f;
                a[e] = (short)bf16u(el);
            }
            #pragma unroll
            for (int ct = 0; ct < 4; ++ct) {
                bf16x8 b = *(const bf16x8*)(Bp + (size_t)ct * 16 * ldb + k0);
                acc[ct] = mfma16(a, b, acc[ct]);
            }
        }
    }
    float a1v[4], a2v[4];
    #pragma unroll
    for (int ct = 0; ct < 4; ++ct) {
        a1v[ct] = a1a[h * 64 + ct * 16 + c16];
        a2v[ct] = a2a[h * 64 + ct * 16 + c16];
    }
    float mx = -1e30f;
    #pragma unroll
    for (int r = 0; r < 4; ++r) {
        float s1 = 0.f, s2 = 0.f;
        int rl = wv * 16 + kg * 4 + r;
        #pragma unroll
        for (int ct = 0; ct < 4; ++ct) {
            float v = acc[ct][r];
            s1 = fmaf(v, a1v[ct], s1);
            s2 = fmaf(v, a2v[ct], s2);
            T[ct * 16 + c16][rl] = bf16u(v);
        }
        #pragma unroll
        for (int off = 1; off < 16; off <<= 1) {
            s1 += __shfl_xor(s1, off, 64);
            s2 += __shfl_xor(s2, off, 64);
        }
        if (c16 == 0) {
            f1o[(size_t)h * N_NODES + bm + rl] = s1;
            f2o[(size_t)h * N_NODES + bm + rl] = s2;
        }
        mx = fmaxf(mx, s2);
    }
    mx = fmaxf(mx, __shfl_xor(mx, 16, 64));
    mx = fmaxf(mx, __shfl_xor(mx, 32, 64));
    if (lane == 0) atomicMax(&gmk[h], fkey(mx));
    __syncthreads();
    const int dd = t >> 2, jc = (t & 3) * 16;
    u16* dst = WhBT + (size_t)(h * 64 + dd) * N_NODES + bm;
    *(uint4*)(dst + jc) = *(const uint4*)&T[dd][jc];
    *(uint4*)(dst + jc + 8) = *(const uint4*)&T[dd][jc + 8];
}

// ---------------- per-row / per-col softmax coefficients ----------------
__global__ void coefk(const float* __restrict__ f1, const float* __restrict__ f2,
                      const unsigned* __restrict__ gmk, float2* __restrict__ rowc,
                      float2* __restrict__ uv) {
    int h = blockIdx.y;
    int i = blockIdx.x * 256 + threadIdx.x;
    float g = funkey(gmk[h]);
    float a = f1[(size_t)h * N_NODES + i];
    float s = a + g;
    float M = lrelu02(s);
    rowc[(size_t)h * N_NODES + i] = make_float2(__expf(s - M), __expf(0.2f * s - M));
    float b = f2[(size_t)h * N_NODES + i] - g;
    uv[(size_t)h * N_NODES + i] = make_float2(__expf(b), __expf(0.2f * b));
}

// ---------------- attention v3 (champion loop) ----------------
// OUTF 1: bf16 row-major partial [js][4096][512] (NH=8)
// OUTF 3: fp32 transposed partial [js][64][4096]  (NH=1)
template <int NH, int ROWS, int JSPLIT, int OUTF>
__global__ __launch_bounds__(256) void attn_v3(
    const u16* __restrict__ WhB, const float2* __restrict__ uv,
    const float2* __restrict__ rowc, const u64* __restrict__ mb,
    void* __restrict__ outp, float* __restrict__ denP) {
    constexpr int NQ = ROWS / 4;
    constexpr int NMT = ROWS / 16;
    constexpr int NJT = (N_NODES / 64) / JSPLIT;
    __shared__ alignas(16) u16 pS[2][ROWS][64];
    __shared__ float Tof[(OUTF == 3) ? 64 * (ROWS + 1) : 1];
    const int b = blockIdx.x;
    int h, ib, js;
    if (NH == 8) { h = b & 7; int r = b >> 3; js = r % JSPLIT; ib = r / JSPLIT; }
    else { h = 0; js = b % JSPLIT; ib = b / JSPLIT; }
    const int i0 = ib * ROWS;
    const int jt0 = js * NJT;
    const int t = threadIdx.x, lane = t & 63, wv = t >> 6;
    const int wv_u = __builtin_amdgcn_readfirstlane(wv);

    const float2* __restrict__ uvp = uv + (size_t)h * N_NODES;
    const float2* __restrict__ rcp = rowc + (size_t)h * N_NODES;
    const u64* __restrict__ mbp = mb + (size_t)(i0 + wv_u) * NW + jt0;

    float Aq[NQ], Bq[NQ], den[NQ];
    #pragma unroll
    for (int q = 0; q < NQ; ++q) {
        float2 rc = rcp[i0 + q * 4 + wv];
        Aq[q] = rc.x; Bq[q] = rc.y; den[q] = 0.f;
    }
    const int wcE = lane ^ (wv << 3);
    const int wcO = lane ^ ((wv + 4) << 3);
    const int kg = lane >> 4, c16 = lane & 15;
    const int ocol = wv * 16 + c16;
    const u16* bptr = WhB + ((size_t)h * 64 + ocol) * N_NODES + jt0 * 64 + kg * 8;
    const int sw8 = (c16 & 7) << 3;
    f32x4 acc[NMT] = {};

    bf16x8 b0 = *(const bf16x8*)(bptr);
    bf16x8 b1 = *(const bf16x8*)(bptr + 32);
    float2 uvv = uvp[jt0 * 64 + lane];
    u64 m[NQ];
    #pragma unroll
    for (int q = 0; q < NQ; ++q) m[q] = mbp[q * 4 * NW];

    for (int it = 0; it < NJT; ++it) {
        const int buf = it & 1;
        const int nit = (it + 1 < NJT) ? it + 1 : it;
        bf16x8 nb0 = *(const bf16x8*)(bptr + (size_t)nit * 64);
        bf16x8 nb1 = *(const bf16x8*)(bptr + (size_t)nit * 64 + 32);
        float2 nuv = uvp[(jt0 + nit) * 64 + lane];
        u64 nm[NQ];
        #pragma unroll
        for (int q = 0; q < NQ; ++q) nm[q] = mbp[q * 4 * NW + nit];
        #pragma unroll
        for (int q = 0; q < NQ; ++q) {
            float tv = fmaxf(Aq[q] * uvv.x, Bq[q] * uvv.y);
            float p;
            asm("v_cndmask_b32 %0, 0, %1, %2" : "=v"(p) : "v"(tv), "s"(m[q]));
            den[q] += p;
            pS[buf][q * 4 + wv][(q & 1) ? wcO : wcE] = bf16u(p);
        }
        __syncthreads();
        __builtin_amdgcn_s_setprio(1);
        #pragma unroll
        for (int mt = 0; mt < NMT; ++mt) {
            const u16* ap = &pS[buf][mt * 16 + c16][0];
            bf16x8 a0 = *(const bf16x8*)&ap[(kg * 8) ^ sw8];
            bf16x8 a1 = *(const bf16x8*)&ap[(32 + kg * 8) ^ sw8];
            acc[mt] = mfma16(a0, b0, acc[mt]);
            acc[mt] = mfma16(a1, b1, acc[mt]);
        }
        __builtin_amdgcn_s_setprio(0);
        b0 = nb0; b1 = nb1; uvv = nuv;
        #pragma unroll
        for (int q = 0; q < NQ; ++q) m[q] = nm[q];
    }

    #pragma unroll
    for (int q = 0; q < NQ; ++q) {
        float s = den[q];
        #pragma unroll
        for (int off = 32; off; off >>= 1) s += __shfl_xor(s, off, 64);
        den[q] = s;
    }

    if constexpr (OUTF == 1) {
        if (lane == 0) {
            #pragma unroll
            for (int q = 0; q < NQ; ++q)
                denP[(size_t)js * (8 * N_NODES) + (size_t)h * N_NODES + i0 + q * 4 + wv] = den[q];
        }
        u16* dst = (u16*)outp + (size_t)js * N_NODES * 512;
        #pragma unroll
        for (int mt = 0; mt < NMT; ++mt)
            #pragma unroll
            for (int r = 0; r < 4; ++r)
                dst[(size_t)(i0 + mt * 16 + kg * 4 + r) * 512 + h * 64 + ocol] =
                    bf16u(acc[mt][r]);
    } else {
        if (lane == 0) {
            #pragma unroll
            for (int q = 0; q < NQ; ++q)
                denP[(size_t)js * N_NODES + i0 + q * 4 + wv] = den[q];
        }
        #pragma unroll
        for (int mt = 0; mt < NMT; ++mt)
            #pragma unroll
            for (int r = 0; r < 4; ++r)
                Tof[ocol * (ROWS + 1) + mt * 16 + kg * 4 + r] = acc[mt][r];
        __syncthreads();
        const int c = t >> 2, r0 = (t & 3) * 8;
        float* dst = (float*)outp + (size_t)js * 64 * N_NODES + (size_t)c * N_NODES + i0 + r0;
        float4 v0 = {Tof[c * (ROWS + 1) + r0 + 0], Tof[c * (ROWS + 1) + r0 + 1],
                     Tof[c * (ROWS + 1) + r0 + 2], Tof[c * (ROWS + 1) + r0 + 3]};
        float4 v1 = {Tof[c * (ROWS + 1) + r0 + 4], Tof[c * (ROWS + 1) + r0 + 5],
                     Tof[c * (ROWS + 1) + r0 + 6], Tof[c * (ROWS + 1) + r0 + 7]};
        *(float4*)(dst) = v0;
        *(float4*)(dst + 4) = v1;
    }
}

// ---------------- combine attn1 partials (8-way) + ELU + log_softmax ---------
__global__ __launch_bounds__(256) void combine1_lsm(
    const float* __restrict__ partT, const float* __restrict__ denp,
    u16* __restrict__ lsT) {
    __shared__ float vb[N_NODES];
    __shared__ float r[256];
    const int c = blockIdx.x, t = threadIdx.x;
    float m = -1e30f;
    for (int i = t * 4; i < N_NODES; i += 1024) {
        float4 s = {0.f, 0.f, 0.f, 0.f}, d = {0.f, 0.f, 0.f, 0.f};
        #pragma unroll
        for (int js = 0; js < 8; ++js) {
            float4 pv = *(const float4*)(partT + (size_t)js * 64 * N_NODES +
                                         (size_t)c * N_NODES + i);
            float4 dv = *(const float4*)(denp + (size_t)js * N_NODES + i);
            s.x += pv.x; s.y += pv.y; s.z += pv.z; s.w += pv.w;
            d.x += dv.x; d.y += dv.y; d.z += dv.z; d.w += dv.w;
        }
        float vv[4] = {d.x > 0.f ? s.x / d.x : 0.f, d.y > 0.f ? s.y / d.y : 0.f,
                       d.z > 0.f ? s.z / d.z : 0.f, d.w > 0.f ? s.w / d.w : 0.f};
        #pragma unroll
        for (int k = 0; k < 4; ++k) {
            float e = vv[k] > 0.f ? vv[k] : expm1f(vv[k]);
            vb[i + k] = e;
            m = fmaxf(m, e);
        }
    }
    r[t] = m;
    __syncthreads();
    for (int s = 128; s; s >>= 1) {
        if (t < s) r[t] = fmaxf(r[t], r[t + s]);
        __syncthreads();
    }
    m = r[0];
    __syncthreads();
    float sum = 0.f;
    for (int i = t; i < N_NODES; i += 256) sum += __expf(vb[i] - m);
    r[t] = sum;
    __syncthreads();
    for (int s = 128; s; s >>= 1) {
        if (t < s) r[t] += r[t + s];
        __syncthreads();
    }
    float lse = m + __logf(r[0]);
    for (int i = t * 4; i < N_NODES; i += 1024) {
        ushort4 o = {bf16u(vb[i] - lse), bf16u(vb[i + 1] - lse),
                     bf16u(vb[i + 2] - lse), bf16u(vb[i + 3] - lse)};
        *(ushort4*)(lsT + (size_t)c * N_NODES + i) = o;
    }
}

// ---------------- mlp1: split-K MFMA  part[ks][64 c][512 o] ----------------
__global__ __launch_bounds__(256) void mlp1_mfma(
    const u16* __restrict__ lsT, const u16* __restrict__ W1B,
    float* __restrict__ part) {
    const int t = threadIdx.x, lane = t & 63, wv = t >> 6;
    const int c16 = lane & 15, kg = lane >> 4;
    const int ks = blockIdx.x & 15;
    const int bn = (blockIdx.x >> 4) * 64;
    const int kb = ks * 256;
    const u16* Ap = lsT + (size_t)(wv * 16 + c16) * N_NODES + kb + kg * 8;
    const u16* Bp = W1B + (size_t)(bn + c16) * N_NODES + kb + kg * 8;
    f32x4 acc[4] = {};
    #pragma unroll
    for (int k0 = 0; k0 < 256; k0 += 32) {
        bf16x8 a = *(const bf16x8*)(Ap + k0);
        #pragma unroll
        for (int ct = 0; ct < 4; ++ct) {
            bf16x8 b = *(const bf16x8*)(Bp + (size_t)ct * 16 * N_NODES + k0);
            acc[ct] = mfma16(a, b, acc[ct]);
        }
    }
    float* dst = part + (size_t)ks * 64 * 512;
    #pragma unroll
    for (int ct = 0; ct < 4; ++ct)
        #pragma unroll
        for (int r = 0; r < 4; ++r)
            dst[(size_t)(wv * 16 + kg * 4 + r) * 512 + bn + ct * 16 + c16] = acc[ct][r];
}

// ---------------- fused: reduce split-K + bias + leaky, then y @ W2^T --------
__global__ __launch_bounds__(256) void mlp2f(
    const float* __restrict__ part, const float* __restrict__ b1,
    const float* __restrict__ W2, const float* __restrict__ b2,
    float* __restrict__ out) {
    __shared__ alignas(16) float row[512];
    const int c = blockIdx.x, t = threadIdx.x;
    #pragma unroll
    for (int half = 0; half < 2; ++half) {
        int o = t + half * 256;
        float s = 0.f;
        #pragma unroll
        for (int ks = 0; ks < 16; ++ks)
            s += part[(size_t)ks * 32768 + (size_t)c * 512 + o];
        s += b1[o];
        row[o] = s > 0.f ? s : 0.1f * s;
    }
    __syncthreads();
    float acc = 0.f;
    #pragma unroll 4
    for (int o = 0; o < 512; o += 4) {
        float4 w4 = *(const float4*)(W2 + (size_t)t * 512 + o);
        float4 r4 = *(const float4*)(&row[o]);
        acc += w4.x * r4.x + w4.y * r4.y + w4.z * r4.z + w4.w * r4.w;
    }
    out[(size_t)c * 256 + t] = acc + b2[t];
}

extern "C" void kernel_launch(void* const* d_in, const int* in_sizes, int n_in,
                              void* d_out, int out_size, void* d_ws, size_t ws_size,
                              hipStream_t stream) {
    const float* x   = (const float*)d_in[0];
    const int*   adj = (const int*)d_in[1];
    const float* W   = (const float*)d_in[2];
    const float* a1  = (const float*)d_in[3];
    const float* a2  = (const float*)d_in[4];
    const float* Wo  = (const float*)d_in[5];
    const float* ao1 = (const float*)d_in[6];
    const float* ao2 = (const float*)d_in[7];
    const float* W1  = (const float*)d_in[8];
    const float* b1  = (const float*)d_in[9];
    const float* W2  = (const float*)d_in[10];
    const float* b2  = (const float*)d_in[11];
    float* out = (float*)d_out;

    char* ws = (char*)d_ws;
    size_t off = 0;
    auto alloc = [&](size_t bytes) {
        void* p = ws + off;
        off += (bytes + 255) & ~(size_t)255;
        return p;
    };
    u64*     mb     = (u64*)alloc((size_t)N_NODES * NW * 8);
    u16*     xB     = (u16*)alloc((size_t)N_NODES * FIN * 2);
    u16*     WBt    = (u16*)alloc((size_t)NHEAD * DHEAD * FIN * 2);
    u16*     WoBt   = (u16*)alloc((size_t)DHEAD * FIN * 2);
    u16*     W1B    = (u16*)alloc((size_t)512 * N_NODES * 2);
    u16*     WhB    = (u16*)alloc((size_t)NHEAD * DHEAD * N_NODES * 2);
    u16*     WhoB   = (u16*)alloc((size_t)DHEAD * N_NODES * 2);
    u16*     part8  = (u16*)alloc((size_t)2 * N_NODES * 512 * 2);     // 8 MB bf16
    char*    pool   = (char*)alloc((size_t)12 << 20);                 // 12 MB pool
    float*   den8   = (float*)alloc((size_t)2 * 8 * N_NODES * 4);
    float*   f1b    = (float*)alloc((size_t)9 * N_NODES * 4);
    float*   f2b    = (float*)alloc((size_t)9 * N_NODES * 4);
    unsigned* gmk   = (unsigned*)alloc(16 * 4);
    float2*  rowc   = (float2*)alloc((size_t)9 * N_NODES * 8);
    float2*  uvb    = (float2*)alloc((size_t)9 * N_NODES * 8);
    float*   partT1 = (float*)pool;                                    // 8 MB [8][64][4096]
    float*   den1   = (float*)(pool + ((size_t)8 << 20));              // 128 KB
    u16*     lsT    = (u16*)(pool + ((size_t)8 << 20) + (256 << 10));  // 512 KB
    float*   part   = (float*)(pool + ((size_t)9 << 20));              // 2 MB
    (void)ws_size; (void)in_sizes; (void)n_in; (void)out_size;

    prep<<<5192, 256, 0, stream>>>(adj, mb, gmk, x, xB, W1, W1B, W, Wo, WBt, WoBt);
    // layer 1
    gemm_fused<0><<<dim3(8, 64), 256, 0, stream>>>(xB, FIN, WBt, FIN, a1, a2,
                                                   WhB, f1b, f2b, gmk, FIN, nullptr);
    coefk<<<dim3(16, 8), 256, 0, stream>>>(f1b, f2b, gmk, rowc, uvb);
    attn_v3<8, 64, 2, 1><<<(N_NODES / 64) * 2 * 8, 256, 0, stream>>>(
        WhB, uvb, rowc, mb, part8, den8);
    // layer 2: gemm consumes the bf16 partials + dens directly (combine fused)
    gemm_fused<1><<<dim3(1, 64), 256, 0, stream>>>(part8, 512, WoBt, FIN, ao1, ao2,
                                                   WhoB, f1b + (size_t)8 * N_NODES,
                                                   f2b + (size_t)8 * N_NODES, gmk + 8,
                                                   FIN, den8);
    coefk<<<dim3(16, 1), 256, 0, stream>>>(f1b + (size_t)8 * N_NODES,
                                           f2b + (size_t)8 * N_NODES, gmk + 8,
                                           rowc + (size_t)8 * N_NODES,
                                           uvb + (size_t)8 * N_NODES);
    attn_v3<1, 32, 8, 3><<<(N_NODES / 32) * 8, 256, 0, stream>>>(
        WhoB, uvb + (size_t)8 * N_NODES, rowc + (size_t)8 * N_NODES, mb, partT1, den1);
    combine1_lsm<<<64, 256, 0, stream>>>(partT1, den1, lsT);
    // MLP head
    mlp1_mfma<<<128, 256, 0, stream>>>(lsT, W1B, part);
    mlp2f<<<64, 256, 0, stream>>>(part, b1, W2, b2, out);
}